// Round 4
// baseline (606.205 us; speedup 1.0000x reference)
//
#include <hip/hip_runtime.h>

#define DF 64

typedef __attribute__((ext_vector_type(8))) short bf16x8;
typedef __attribute__((ext_vector_type(2))) short v2s;
typedef __attribute__((ext_vector_type(4))) float f32x4;
typedef unsigned int u32;

__device__ __forceinline__ short f2bf(float f) {
    union { float f; unsigned u; } v; v.f = f;
    unsigned u = v.u;
    u += 0x7FFFu + ((u >> 16) & 1u);   // RNE
    return (short)(u >> 16);
}

__device__ __forceinline__ float bf2f(unsigned s) {
    union { unsigned u; float f; } v; v.u = s << 16;
    return v.f;
}

__device__ __forceinline__ bf16x8 cvt8(float4 a, float4 b) {
    bf16x8 r;
    r[0] = f2bf(a.x); r[1] = f2bf(a.y); r[2] = f2bf(a.z); r[3] = f2bf(a.w);
    r[4] = f2bf(b.x); r[5] = f2bf(b.y); r[6] = f2bf(b.z); r[7] = f2bf(b.w);
    return r;
}

// packed bf16x2 atomic add (fallback path only)
__device__ __forceinline__ void pk_add(short* addr, int val) {
#if __has_builtin(__builtin_amdgcn_global_atomic_fadd_v2bf16)
    __builtin_amdgcn_global_atomic_fadd_v2bf16(
        (__attribute__((address_space(1))) v2s*)addr, *(v2s*)&val);
#else
    unsigned* a = (unsigned*)addr;
    unsigned old = *a, assumed;
    do {
        assumed = old;
        float lo = bf2f(assumed & 0xffffu) + bf2f((unsigned)val & 0xffffu);
        float hi = bf2f(assumed >> 16)     + bf2f((unsigned)val >> 16);
        unsigned nv = (unsigned)(unsigned short)f2bf(lo) |
                      ((unsigned)(unsigned short)f2bf(hi) << 16);
        old = atomicCAS(a, assumed, nv);
    } while (old != assumed);
#endif
}

// Transpose + convert the 4 weight matrices to bf16 [n][k] (B^T) once per launch.
__global__ __launch_bounds__(256) void prep_weights(
    const float* __restrict__ w1a, const float* __restrict__ w1b,
    const float* __restrict__ w2a, const float* __restrict__ w2b,
    short* __restrict__ w1aT, short* __restrict__ w1bT,
    short* __restrict__ w2aT, short* __restrict__ w2bT)
{
    int gid = blockIdx.x * 256 + threadIdx.x;   // 24576 total
    if (gid < 8192) {
        int k = gid >> 6, n = gid & 63;
        w1aT[n * 128 + k] = f2bf(w1a[gid]);
    } else if (gid < 12288) {
        int g = gid - 8192; int k = g >> 6, n = g & 63;
        w1bT[n * 64 + k] = f2bf(w1b[g]);
    } else if (gid < 20480) {
        int g = gid - 12288; int k = g >> 6, n = g & 63;
        w2aT[n * 128 + k] = f2bf(w2a[g]);
    } else if (gid < 24576) {
        int g = gid - 20480; int k = g >> 6, n = g & 63;
        w2bT[n * 64 + k] = f2bf(w2b[g]);
    }
}

// ---------------- CSR build ----------------

__global__ __launch_bounds__(256) void degree_hist(
    const int* __restrict__ ei, u32* __restrict__ deg, int E)
{
    int e = blockIdx.x * 256 + threadIdx.x;
    if (e < E) atomicAdd(&deg[ei[E + e]], 1u);
}

// Single-block exclusive scan of deg[0..NN) -> off[0..NN], cursor copy.
__global__ __launch_bounds__(1024) void scan_offsets(
    const u32* __restrict__ deg, u32* __restrict__ off,
    u32* __restrict__ cursor, int NN)
{
    __shared__ u32 wtot[16];
    __shared__ u32 carry_s;
    const int t = threadIdx.x, lane = t & 63, wv = t >> 6;
    if (t == 0) carry_s = 0;
    __syncthreads();
    for (int base = 0; base < NN; base += 1024) {
        int i = base + t;
        u32 v = (i < NN) ? deg[i] : 0u;
        u32 x = v;
#pragma unroll
        for (int d = 1; d < 64; d <<= 1) {
            u32 n = __shfl_up(x, (unsigned)d, 64);
            if (lane >= d) x += n;
        }
        if (lane == 63) wtot[wv] = x;
        __syncthreads();
        u32 chunk_total = 0;
        if (t == 0) {
            u32 s = 0;
            for (int k2 = 0; k2 < 16; ++k2) { u32 tv = wtot[k2]; wtot[k2] = s; s += tv; }
            chunk_total = s;
        }
        __syncthreads();
        u32 excl = carry_s + wtot[wv] + x - v;
        if (i < NN) { off[i] = excl; cursor[i] = excl; }
        __syncthreads();
        if (t == 0) carry_s += chunk_total;
        __syncthreads();
    }
    if (t == 0) off[NN] = carry_s;
}

__global__ __launch_bounds__(256) void bucket_edges(
    const int* __restrict__ ei, u32* __restrict__ cursor,
    u32* __restrict__ perm, int E)
{
    int e = blockIdx.x * 256 + threadIdx.x;
    if (e < E) {
        u32 pos = atomicAdd(&cursor[ei[E + e]], 1u);
        perm[pos] = (u32)e;
    }
}

// ---------------- CSR path main kernels ----------------

// Edge MLP -> streamed bf16 h rows (no atomics). One 16-edge M-tile per wave.
__global__ __launch_bounds__(256, 8) void edge_mlp_h(
    const float* __restrict__ x, const int* __restrict__ ei,
    const float* __restrict__ ea,
    const short* __restrict__ w1aT, const float* __restrict__ b1a,
    const short* __restrict__ w1bT, const float* __restrict__ b1b,
    short* __restrict__ h, int E)
{
    __shared__ alignas(16) short lsH[4 * 16 * 72];   // 9.2 KB, wave-private slices

    const int t = threadIdx.x;
    const int lane = t & 63;
    const int w = t >> 6;
    const int q = lane >> 4;
    const int m = lane & 15;
    const long base = ((long)blockIdx.x * 4 + w) * 16;

    const long e = base + m;
    const long ec = e < E ? e : (long)(E - 1);
    const int row = ei[ec];

    const float4* xr = (const float4*)(x + (long)row * DF);
    const float4* er = (const float4*)(ea + ec * DF);
    bf16x8 afr[4];
    afr[0] = cvt8(xr[q * 2],     xr[q * 2 + 1]);
    afr[1] = cvt8(xr[8 + q * 2], xr[8 + q * 2 + 1]);
    afr[2] = cvt8(er[q * 2],     er[q * 2 + 1]);
    afr[3] = cvt8(er[8 + q * 2], er[8 + q * 2 + 1]);

    f32x4 acc[4];
#pragma unroll
    for (int nt = 0; nt < 4; ++nt) {
        float b = b1a[nt * 16 + m];
        f32x4 v = {b, b, b, b};
        acc[nt] = v;
#pragma unroll
        for (int ks = 0; ks < 4; ++ks) {
            bf16x8 bfr = *(const bf16x8*)&w1aT[(nt * 16 + m) * 128 + ks * 32 + q * 8];
            acc[nt] = __builtin_amdgcn_mfma_f32_16x16x32_bf16(afr[ks], bfr, acc[nt], 0, 0, 0);
        }
    }

    short* hw = lsH + w * (16 * 72);
#pragma unroll
    for (int nt = 0; nt < 4; ++nt)
#pragma unroll
        for (int r = 0; r < 4; ++r) {
            float v = acc[nt][r] > 0.f ? acc[nt][r] : 0.f;
            hw[(q * 4 + r) * 72 + nt * 16 + m] = f2bf(v);
        }
    __syncthreads();

    bf16x8 a2[2];
    a2[0] = *(const bf16x8*)&hw[m * 72 + q * 8];
    a2[1] = *(const bf16x8*)&hw[m * 72 + 32 + q * 8];

    f32x4 acc2[4];
#pragma unroll
    for (int nt = 0; nt < 4; ++nt) {
        float b = b1b[nt * 16 + m];
        f32x4 v = {b, b, b, b};
        acc2[nt] = v;
#pragma unroll
        for (int ks = 0; ks < 2; ++ks) {
            bf16x8 bfr = *(const bf16x8*)&w1bT[(nt * 16 + m) * 64 + ks * 32 + q * 8];
            acc2[nt] = __builtin_amdgcn_mfma_f32_16x16x32_bf16(a2[ks], bfr, acc2[nt], 0, 0, 0);
        }
    }
    __syncthreads();

    // D-layout -> row-major bf16 in LDS, then streamed 16B global stores
#pragma unroll
    for (int nt = 0; nt < 4; ++nt)
#pragma unroll
        for (int r = 0; r < 4; ++r)
            hw[(q * 4 + r) * 72 + nt * 16 + m] = f2bf(acc2[nt][r]);
    __syncthreads();

    const int* hwi = (const int*)hw;
    int* ho = (int*)h;
    const int p4 = lane & 7;       // int4 index within the 32-int row
    const int rr = lane >> 3;      // 8 rows per pass
#pragma unroll
    for (int i = 0; i < 2; ++i) {
        int r2 = rr + 8 * i;
        long eg = base + r2;
        if (eg < E) {
            int4 v = *(const int4*)&hwi[r2 * 36 + p4 * 4];
            *(int4*)&ho[eg * 32 + p4 * 4] = v;
        }
    }
}

// Fused aggregation (CSR gather, fp32 accumulate, mean) + node MLP.
__global__ __launch_bounds__(256, 4) void node_mlp_agg(
    const float* __restrict__ x, const short* __restrict__ h,
    const u32* __restrict__ off, const u32* __restrict__ perm,
    const short* __restrict__ w2aT, const float* __restrict__ b2a,
    const short* __restrict__ w2bT, const float* __restrict__ b2b,
    float* __restrict__ out, int NN)
{
    __shared__ alignas(16) short lsH[4 * 16 * 72];

    const int t = threadIdx.x;
    const int lane = t & 63;
    const int w = t >> 6;
    const int q = lane >> 4;
    const int m = lane & 15;
    const long base = ((long)blockIdx.x * 4 + w) * 16;

    const long node = base + m;
    const bool valid = node < NN;
    const long nc = valid ? node : (long)(NN - 1);

    const u32 o0 = off[nc];
    const int deg = valid ? (int)(off[nc + 1] - o0) : 0;

    float sa[8] = {0,0,0,0,0,0,0,0}, sb[8] = {0,0,0,0,0,0,0,0};
    for (int j = 0; j < deg; ++j) {
        int eid = (int)perm[o0 + j];
        const short* hr = h + (long)eid * DF;
        bf16x8 ha = *(const bf16x8*)(hr + q * 8);
        bf16x8 hb = *(const bf16x8*)(hr + 32 + q * 8);
#pragma unroll
        for (int i = 0; i < 8; ++i) {
            sa[i] += bf2f((unsigned short)ha[i]);
            sb[i] += bf2f((unsigned short)hb[i]);
        }
    }
    const float inv = deg > 0 ? 1.f / (float)deg : 1.f;

    const float4* xr = (const float4*)(x + nc * DF);
    bf16x8 afr[4];
    afr[0] = cvt8(xr[q * 2],     xr[q * 2 + 1]);
    afr[1] = cvt8(xr[8 + q * 2], xr[8 + q * 2 + 1]);
#pragma unroll
    for (int i = 0; i < 8; ++i) {
        afr[2][i] = f2bf(sa[i] * inv);
        afr[3][i] = f2bf(sb[i] * inv);
    }

    f32x4 acc[4];
#pragma unroll
    for (int nt = 0; nt < 4; ++nt) {
        float b = b2a[nt * 16 + m];
        f32x4 v = {b, b, b, b};
        acc[nt] = v;
#pragma unroll
        for (int ks = 0; ks < 4; ++ks) {
            bf16x8 bfr = *(const bf16x8*)&w2aT[(nt * 16 + m) * 128 + ks * 32 + q * 8];
            acc[nt] = __builtin_amdgcn_mfma_f32_16x16x32_bf16(afr[ks], bfr, acc[nt], 0, 0, 0);
        }
    }

    short* hw = lsH + w * (16 * 72);
#pragma unroll
    for (int nt = 0; nt < 4; ++nt)
#pragma unroll
        for (int r = 0; r < 4; ++r) {
            float v = acc[nt][r] > 0.f ? acc[nt][r] : 0.f;
            hw[(q * 4 + r) * 72 + nt * 16 + m] = f2bf(v);
        }
    __syncthreads();

    bf16x8 a2[2];
    a2[0] = *(const bf16x8*)&hw[m * 72 + q * 8];
    a2[1] = *(const bf16x8*)&hw[m * 72 + 32 + q * 8];

    f32x4 acc2[4];
#pragma unroll
    for (int nt = 0; nt < 4; ++nt) {
        float b = b2b[nt * 16 + m];
        f32x4 v = {b, b, b, b};
        acc2[nt] = v;
#pragma unroll
        for (int ks = 0; ks < 2; ++ks) {
            bf16x8 bfr = *(const bf16x8*)&w2bT[(nt * 16 + m) * 64 + ks * 32 + q * 8];
            acc2[nt] = __builtin_amdgcn_mfma_f32_16x16x32_bf16(a2[ks], bfr, acc2[nt], 0, 0, 0);
        }
    }

#pragma unroll
    for (int r = 0; r < 4; ++r) {
        long n2 = base + q * 4 + r;
        if (n2 < NN) {
#pragma unroll
            for (int nt = 0; nt < 4; ++nt)
                out[n2 * DF + nt * 16 + m] = acc2[nt][r];
        }
    }
}

// ---------------- fallback (atomic) path kernels — round-3 proven ----------------

__global__ __launch_bounds__(256, 8) void edge_mlp_scatter(
    const float* __restrict__ x, const int* __restrict__ ei,
    const float* __restrict__ ea,
    const short* __restrict__ w1aT, const float* __restrict__ b1a,
    const short* __restrict__ w1bT, const float* __restrict__ b1b,
    short* __restrict__ summedh, float* __restrict__ counts, int E)
{
    __shared__ alignas(16) short lsH[4 * 16 * 72];

    const int t = threadIdx.x;
    const int lane = t & 63;
    const int w = t >> 6;
    const int q = lane >> 4;
    const int m = lane & 15;
    const long base = ((long)blockIdx.x * 4 + w) * 16;

    const long e = base + m;
    const long ec = e < E ? e : (long)(E - 1);
    const int row = ei[ec];

    if (q == 0 && e < E)
        unsafeAtomicAdd(&counts[ei[E + e]], 1.0f);

    const float4* xr = (const float4*)(x + (long)row * DF);
    const float4* er = (const float4*)(ea + ec * DF);
    bf16x8 afr[4];
    afr[0] = cvt8(xr[q * 2],     xr[q * 2 + 1]);
    afr[1] = cvt8(xr[8 + q * 2], xr[8 + q * 2 + 1]);
    afr[2] = cvt8(er[q * 2],     er[q * 2 + 1]);
    afr[3] = cvt8(er[8 + q * 2], er[8 + q * 2 + 1]);

    f32x4 acc[4];
#pragma unroll
    for (int nt = 0; nt < 4; ++nt) {
        float b = b1a[nt * 16 + m];
        f32x4 v = {b, b, b, b};
        acc[nt] = v;
#pragma unroll
        for (int ks = 0; ks < 4; ++ks) {
            bf16x8 bfr = *(const bf16x8*)&w1aT[(nt * 16 + m) * 128 + ks * 32 + q * 8];
            acc[nt] = __builtin_amdgcn_mfma_f32_16x16x32_bf16(afr[ks], bfr, acc[nt], 0, 0, 0);
        }
    }

    short* hw = lsH + w * (16 * 72);
#pragma unroll
    for (int nt = 0; nt < 4; ++nt)
#pragma unroll
        for (int r = 0; r < 4; ++r) {
            float v = acc[nt][r] > 0.f ? acc[nt][r] : 0.f;
            hw[(q * 4 + r) * 72 + nt * 16 + m] = f2bf(v);
        }
    __syncthreads();

    bf16x8 a2[2];
    a2[0] = *(const bf16x8*)&hw[m * 72 + q * 8];
    a2[1] = *(const bf16x8*)&hw[m * 72 + 32 + q * 8];

    f32x4 acc2[4];
#pragma unroll
    for (int nt = 0; nt < 4; ++nt) {
        float b = b1b[nt * 16 + m];
        f32x4 v = {b, b, b, b};
        acc2[nt] = v;
#pragma unroll
        for (int ks = 0; ks < 2; ++ks) {
            bf16x8 bfr = *(const bf16x8*)&w1bT[(nt * 16 + m) * 64 + ks * 32 + q * 8];
            acc2[nt] = __builtin_amdgcn_mfma_f32_16x16x32_bf16(a2[ks], bfr, acc2[nt], 0, 0, 0);
        }
    }
    __syncthreads();

#pragma unroll
    for (int nt = 0; nt < 4; ++nt)
#pragma unroll
        for (int r = 0; r < 4; ++r)
            hw[(q * 4 + r) * 72 + nt * 16 + m] = f2bf(acc2[nt][r]);
    __syncthreads();

    const int p = lane & 31;
    const int* hwi = (const int*)hw;
#pragma unroll
    for (int i = 0; i < 8; ++i) {
        int r2 = (lane >> 5) + 2 * i;
        long eg = base + r2;
        if (eg < E) {
            int dst = ei[E + eg];
            int val = hwi[r2 * 36 + p];
            pk_add(&summedh[(long)dst * DF + 2 * p], val);
        }
    }
}

__global__ __launch_bounds__(256, 8) void node_mlp(
    const float* __restrict__ x, const short* __restrict__ summedh,
    const float* __restrict__ counts,
    const short* __restrict__ w2aT, const float* __restrict__ b2a,
    const short* __restrict__ w2bT, const float* __restrict__ b2b,
    float* __restrict__ out, int NN)
{
    __shared__ alignas(16) short lsH[4 * 16 * 72];

    const int t = threadIdx.x;
    const int lane = t & 63;
    const int w = t >> 6;
    const int q = lane >> 4;
    const int m = lane & 15;
    const long base = ((long)blockIdx.x * 4 + w) * 16;

    const long node = base + m;
    const long nc = node < NN ? node : (long)(NN - 1);

    const float4* xr = (const float4*)(x + nc * DF);
    float c = counts[nc];
    c = c > 1.f ? c : 1.f;
    const float inv = 1.f / c;

    bf16x8 s0 = *(const bf16x8*)&summedh[nc * DF + q * 8];
    bf16x8 s1 = *(const bf16x8*)&summedh[nc * DF + 32 + q * 8];

    bf16x8 afr[4];
    afr[0] = cvt8(xr[q * 2],     xr[q * 2 + 1]);
    afr[1] = cvt8(xr[8 + q * 2], xr[8 + q * 2 + 1]);
#pragma unroll
    for (int i = 0; i < 8; ++i) {
        afr[2][i] = f2bf(bf2f((unsigned short)s0[i]) * inv);
        afr[3][i] = f2bf(bf2f((unsigned short)s1[i]) * inv);
    }

    f32x4 acc[4];
#pragma unroll
    for (int nt = 0; nt < 4; ++nt) {
        float b = b2a[nt * 16 + m];
        f32x4 v = {b, b, b, b};
        acc[nt] = v;
#pragma unroll
        for (int ks = 0; ks < 4; ++ks) {
            bf16x8 bfr = *(const bf16x8*)&w2aT[(nt * 16 + m) * 128 + ks * 32 + q * 8];
            acc[nt] = __builtin_amdgcn_mfma_f32_16x16x32_bf16(afr[ks], bfr, acc[nt], 0, 0, 0);
        }
    }

    short* hw = lsH + w * (16 * 72);
#pragma unroll
    for (int nt = 0; nt < 4; ++nt)
#pragma unroll
        for (int r = 0; r < 4; ++r) {
            float v = acc[nt][r] > 0.f ? acc[nt][r] : 0.f;
            hw[(q * 4 + r) * 72 + nt * 16 + m] = f2bf(v);
        }
    __syncthreads();

    bf16x8 a2[2];
    a2[0] = *(const bf16x8*)&hw[m * 72 + q * 8];
    a2[1] = *(const bf16x8*)&hw[m * 72 + 32 + q * 8];

    f32x4 acc2[4];
#pragma unroll
    for (int nt = 0; nt < 4; ++nt) {
        float b = b2b[nt * 16 + m];
        f32x4 v = {b, b, b, b};
        acc2[nt] = v;
#pragma unroll
        for (int ks = 0; ks < 2; ++ks) {
            bf16x8 bfr = *(const bf16x8*)&w2bT[(nt * 16 + m) * 64 + ks * 32 + q * 8];
            acc2[nt] = __builtin_amdgcn_mfma_f32_16x16x32_bf16(a2[ks], bfr, acc2[nt], 0, 0, 0);
        }
    }

#pragma unroll
    for (int r = 0; r < 4; ++r) {
        long n2 = base + q * 4 + r;
        if (n2 < NN) {
#pragma unroll
            for (int nt = 0; nt < 4; ++nt)
                out[n2 * DF + nt * 16 + m] = acc2[nt][r];
        }
    }
}

extern "C" void kernel_launch(void* const* d_in, const int* in_sizes, int n_in,
                              void* d_out, int out_size, void* d_ws, size_t ws_size,
                              hipStream_t stream) {
    const float* x   = (const float*)d_in[0];
    const int*   ei  = (const int*)d_in[1];
    const float* ea  = (const float*)d_in[2];
    const float* w1a = (const float*)d_in[5];
    const float* b1a = (const float*)d_in[6];
    const float* w1b = (const float*)d_in[7];
    const float* b1b = (const float*)d_in[8];
    const float* w2a = (const float*)d_in[9];
    const float* b2a = (const float*)d_in[10];
    const float* w2b = (const float*)d_in[11];
    const float* b2b = (const float*)d_in[12];

    const int NN = in_sizes[0] / DF;   // 50000
    const int E  = in_sizes[2] / DF;   // 800000

    char* wsb = (char*)d_ws;

    // CSR-path workspace layout
    const size_t oDeg  = 0;                 // NN u32
    const size_t oOff  = 262144;            // NN+1 u32
    const size_t oCur  = 524288;            // NN u32
    const size_t oPerm = 786432;            // E u32 (3.2 MB)
    const size_t oW    = 4194304;           // 48 KB weights
    const size_t oH    = 4259840;           // E*128 B bf16 h rows
    const size_t need  = oH + (size_t)E * DF * sizeof(short);

    if (ws_size >= need) {
        u32* deg    = (u32*)(wsb + oDeg);
        u32* off    = (u32*)(wsb + oOff);
        u32* cursor = (u32*)(wsb + oCur);
        u32* perm   = (u32*)(wsb + oPerm);
        short* w1aT = (short*)(wsb + oW);
        short* w1bT = (short*)(wsb + oW + 16384);
        short* w2aT = (short*)(wsb + oW + 24576);
        short* w2bT = (short*)(wsb + oW + 40960);
        short* h    = (short*)(wsb + oH);

        hipMemsetAsync(deg, 0, (size_t)NN * sizeof(u32), stream);
        prep_weights<<<96, 256, 0, stream>>>(w1a, w1b, w2a, w2b, w1aT, w1bT, w2aT, w2bT);

        int e256 = (E + 255) / 256;
        degree_hist<<<e256, 256, 0, stream>>>(ei, deg, E);
        scan_offsets<<<1, 1024, 0, stream>>>(deg, off, cursor, NN);
        bucket_edges<<<e256, 256, 0, stream>>>(ei, cursor, perm, E);

        int eblocks = ((E + 15) / 16 + 3) / 4;
        edge_mlp_h<<<eblocks, 256, 0, stream>>>(x, ei, ea, w1aT, b1a, w1bT, b1b, h, E);

        int nblocks = ((NN + 15) / 16 + 3) / 4;
        node_mlp_agg<<<nblocks, 256, 0, stream>>>(x, h, off, perm, w2aT, b2a, w2bT, b2b,
                                                  (float*)d_out, NN);
    } else {
        // fallback: round-3 atomic path
        float* counts  = (float*)wsb;
        short* w1aT    = (short*)(wsb + 262144);
        short* w1bT    = (short*)(wsb + 278528);
        short* w2aT    = (short*)(wsb + 286720);
        short* w2bT    = (short*)(wsb + 303104);
        short* summedh = (short*)(wsb + 311296);

        hipMemsetAsync(counts, 0, (size_t)NN * sizeof(float), stream);
        hipMemsetAsync(summedh, 0, (size_t)NN * DF * sizeof(short), stream);
        prep_weights<<<96, 256, 0, stream>>>(w1a, w1b, w2a, w2b, w1aT, w1bT, w2aT, w2bT);

        int eblocks = ((E + 15) / 16 + 3) / 4;
        edge_mlp_scatter<<<eblocks, 256, 0, stream>>>(x, ei, ea, w1aT, b1a, w1bT, b1b,
                                                      summedh, counts, E);
        int nblocks = ((NN + 15) / 16 + 3) / 4;
        node_mlp<<<nblocks, 256, 0, stream>>>(x, summedh, counts, w2aT, b2a, w2bT, b2b,
                                              (float*)d_out, NN);
    }
}